// Round 3
// baseline (407.772 us; speedup 1.0000x reference)
//
#include <hip/hip_runtime.h>

// Bloch RK4 trajectory integrator — log-depth chunk starts + LDS store-transpose.
//
// B=65536 systems, T=512 outputs, RK4, 3-state LINEAR ODE per system:
//   u' = -g u ;  (v,w)' = A2 (v,w) + b2,  A2=[[-g,-Om],[Om,-2g]], b2=(0,-2g).
//
// Round 0-2 lesson: with one thread per system, per-row stores are 3 scalar
// dwords at 12 B lane stride -> each store instruction partially touches 12
// cache lines -> ~1.0 TB/s effective write BW (rounds 0/1/2 all fit this
// single constant). Fix: stage 4 output rows (4 x 3 KB) in LDS, flush as
// wave-contiguous float4 stores (1 KB/instruction, full lines) — the same
// pattern the runtime's fillBuffer sustains 6.2 TB/s with.
//
// Parallelism (from round 2): one thread per (system, chunk of 32 steps).
// Chunk-start states computed in O(log) via the exact RK4-on-linear affine
// map (P = T4(dt*A2)) with 5 affine doublings; then 31 bit-identical scalar
// RK4 replay steps produce the stored rows.

#define NB 65536
#define NT 512
#define CHUNK 32
#define NCH (NT / CHUNK)      // 16 chunks
#define NB3 (NB * 3)          // floats per output row
#define NB3V (NB3 / 4)        // float4 per output row
#define RB 4                  // rows buffered in LDS per flush

__device__ __forceinline__ void rk4_step(
    float& u, float& v, float& w,
    const float Om, const float g, const float g2, const float dt)
{
    const float k1u = -g * u;
    const float k1v = -g * v - Om * w;
    const float k1w = Om * v - g2 * w - g2;

    const float h = 0.5f * dt;
    float uu = u + h * k1u;
    float vv = v + h * k1v;
    float ww = w + h * k1w;

    const float k2u = -g * uu;
    const float k2v = -g * vv - Om * ww;
    const float k2w = Om * vv - g2 * ww - g2;

    uu = u + h * k2u;
    vv = v + h * k2v;
    ww = w + h * k2w;

    const float k3u = -g * uu;
    const float k3v = -g * vv - Om * ww;
    const float k3w = Om * vv - g2 * ww - g2;

    uu = u + dt * k3u;
    vv = v + dt * k3v;
    ww = w + dt * k3w;

    const float k4u = -g * uu;
    const float k4v = -g * vv - Om * ww;
    const float k4w = Om * vv - g2 * ww - g2;

    const float s = dt * (1.0f / 6.0f);
    u += s * (k1u + 2.0f * k2u + 2.0f * k3u + k4u);
    v += s * (k1v + 2.0f * k2v + 2.0f * k3v + k4v);
    w += s * (k1w + 2.0f * k2w + 2.0f * k3w + k4w);
}

__global__ __launch_bounds__(256) void bloch_rk4(
    const float* __restrict__ y0,
    const float* __restrict__ tspan,
    const float* __restrict__ params,
    float* __restrict__ out)
{
    __shared__ float sdt[CHUNK];
    __shared__ float srow[RB][768];   // 4 rows x 256 systems x 3 floats = 12 KB

    const int tid = threadIdx.x;
    const int bx  = blockIdx.x;
    const int j   = bx & (NCH - 1);   // chunk index 0..15 (uniform per block)
    const int sg  = bx >> 4;          // system group 0..255
    const int i0  = j * CHUNK;        // first output row owned by this block

    if (tid < CHUNK) {
        const int idx = i0 + tid;
        float d = 0.0f;
        if (idx + 1 < NT) d = tspan[idx + 1] - tspan[idx];
        sdt[tid] = d;
    }
    __syncthreads();

    const int b   = sg * 256 + tid;
    const int ib3 = b * 3;
    const float Om = params[ib3 + 0];
    const float g  = params[ib3 + 2];
    const float g2 = 2.0f * g;

    float u = y0[ib3 + 0];
    float v = y0[ib3 + 1];
    float w = y0[ib3 + 2];

    if (j > 0) {
        // ---- one-step affine map: P = T4(N), d = dt0*E*b2, N = dt0*A2 ----
        const float dt0 = tspan[1] - tspan[0];
        const float n00 = -g  * dt0;
        const float n01 = -Om * dt0;
        const float n10 =  Om * dt0;
        const float n11 = -g2 * dt0;

        float e00 = 1.0f + 0.25f * n00, e01 = 0.25f * n01;
        float e10 = 0.25f * n10,        e11 = 1.0f + 0.25f * n11;
        {
            const float t00 = n00 * (1.0f / 3.0f), t01 = n01 * (1.0f / 3.0f);
            const float t10 = n10 * (1.0f / 3.0f), t11 = n11 * (1.0f / 3.0f);
            const float f00 = 1.0f + t00 * e00 + t01 * e10;
            const float f01 =        t00 * e01 + t01 * e11;
            const float f10 =        t10 * e00 + t11 * e10;
            const float f11 = 1.0f + t10 * e01 + t11 * e11;
            e00 = f00; e01 = f01; e10 = f10; e11 = f11;
        }
        {
            const float t00 = 0.5f * n00, t01 = 0.5f * n01;
            const float t10 = 0.5f * n10, t11 = 0.5f * n11;
            const float f00 = 1.0f + t00 * e00 + t01 * e10;
            const float f01 =        t00 * e01 + t01 * e11;
            const float f10 =        t10 * e00 + t11 * e10;
            const float f11 = 1.0f + t10 * e01 + t11 * e11;
            e00 = f00; e01 = f01; e10 = f10; e11 = f11;
        }
        float p00 = 1.0f + n00 * e00 + n01 * e10;
        float p01 =        n00 * e01 + n01 * e11;
        float p10 =        n10 * e00 + n11 * e10;
        float p11 = 1.0f + n10 * e01 + n11 * e11;
        float dv = dt0 * (e01 * -g2);
        float dw = dt0 * (e11 * -g2);
        const float a  = -g * dt0;
        const float eu = 1.0f + 0.5f * a * (1.0f + (a * (1.0f / 3.0f)) * (1.0f + 0.25f * a));
        float al = 1.0f + a * eu;

        // ---- 5 affine doublings: S_2n = S_n + P^n S_n ; P -> P^2 ----
        float s00 = 1.0f, s01 = 0.0f, s10 = 0.0f, s11 = 1.0f;
#pragma unroll
        for (int k = 0; k < 5; ++k) {
            const float q00 = s00 + p00 * s00 + p01 * s10;
            const float q01 = s01 + p00 * s01 + p01 * s11;
            const float q10 = s10 + p10 * s00 + p11 * s10;
            const float q11 = s11 + p10 * s01 + p11 * s11;
            const float r00 = p00 * p00 + p01 * p10;
            const float r01 = p00 * p01 + p01 * p11;
            const float r10 = p10 * p00 + p11 * p10;
            const float r11 = p10 * p01 + p11 * p11;
            s00 = q00; s01 = q01; s10 = q10; s11 = q11;
            p00 = r00; p01 = r01; p10 = r10; p11 = r11;
            al = al * al;
        }
        const float ev = s00 * dv + s01 * dw;
        const float ew = s10 * dv + s11 * dw;

        for (int m = 0; m < j; ++m) {
            const float nv = p00 * v + p01 * w + ev;
            const float nw = p10 * v + p11 * w + ew;
            v = nv; w = nw;
            u = al * u;
        }
    }

    // ---- rows i0..i0+31: stage in LDS (AoS), flush every 4 rows as float4 ----
    float4* __restrict__ out4 = (float4*)out;
    const int colbase = sg * 192;      // this block's float4 column offset

    // row 0 of the chunk
    srow[0][3 * tid + 0] = u;
    srow[0][3 * tid + 1] = v;
    srow[0][3 * tid + 2] = w;

    float dt = sdt[0];
    for (int r = 1; r < CHUNK; ++r) {
        const float dtn = sdt[r];      // prefetch next dt
        rk4_step(u, v, w, Om, g, g2, dt);
        const int rb = r & (RB - 1);
        srow[rb][3 * tid + 0] = u;
        srow[rb][3 * tid + 1] = v;
        srow[rb][3 * tid + 2] = w;
        dt = dtn;
        if (rb == RB - 1) {
            __syncthreads();
            const int rowbase = i0 + r - (RB - 1);
#pragma unroll
            for (int q = 0; q < 3; ++q) {          // 4 rows x 192 float4 = 768
                const int flat = q * 256 + tid;    // 0..767
                const int row  = flat / 192;       // 0..3
                const int col  = flat - row * 192; // 0..191
                const float4 val = *(const float4*)&srow[row][col * 4];
                out4[(size_t)(rowbase + row) * NB3V + (size_t)(colbase + col)] = val;
            }
            __syncthreads();
        }
    }
}

extern "C" void kernel_launch(void* const* d_in, const int* in_sizes, int n_in,
                              void* d_out, int out_size, void* d_ws, size_t ws_size,
                              hipStream_t stream) {
    const float* y0     = (const float*)d_in[0];
    const float* tspan  = (const float*)d_in[1];
    const float* params = (const float*)d_in[2];
    float* out = (float*)d_out;

    bloch_rk4<<<(NB / 256) * NCH, 256, 0, stream>>>(y0, tspan, params, out);
}